// Round 1
// baseline (151.724 us; speedup 1.0000x reference)
//
#include <hip/hip_runtime.h>
#include <math.h>

#define BB 16
#define NN 4096
#define CC 512
#define C2 256
#define CHUNKS 64
#define RPC (NN/CHUNKS)   // 64 rows per chunk

__device__ __forceinline__ float sigmoidf_(float z){ return 1.0f/(1.0f + __expf(-z)); }

// ---------------- K1: per-pixel channel-attention logits  s1[row] = x[row,:]·wq + bq
__global__ __launch_bounds__(256) void k_logits(const float* __restrict__ x,
        const float* __restrict__ wq, const float* __restrict__ bq,
        float* __restrict__ s1)
{
    const int lane = threadIdx.x & 63;
    const int wv   = threadIdx.x >> 6;
    const long row = (long)blockIdx.x * 4 + wv;      // one wave per row
    const float* xr = x + row * CC;
    float4 a0 = *(const float4*)(xr + lane*4);
    float4 a1 = *(const float4*)(xr + 256 + lane*4);
    float4 w0 = *(const float4*)(wq + lane*4);
    float4 w1 = *(const float4*)(wq + 256 + lane*4);
    float d = a0.x*w0.x + a0.y*w0.y + a0.z*w0.z + a0.w*w0.w
            + a1.x*w1.x + a1.y*w1.y + a1.z*w1.z + a1.w*w1.w;
    #pragma unroll
    for (int off = 32; off; off >>= 1) d += __shfl_xor(d, off);
    if (lane == 0) s1[row] = d + bq[0];
}

// ---------------- K2: softmax over N per batch (p = softmax(s1, axis=n))
__global__ __launch_bounds__(256) void k_softmax_n(const float* __restrict__ s1,
                                                   float* __restrict__ p)
{
    const int b = blockIdx.x, tid = threadIdx.x, lane = tid & 63, w = tid >> 6;
    __shared__ float red[4];
    const float* s = s1 + b * NN;
    float m = -3.4e38f;
    for (int i = tid; i < NN; i += 256) m = fmaxf(m, s[i]);
    #pragma unroll
    for (int off = 32; off; off >>= 1) m = fmaxf(m, __shfl_xor(m, off));
    if (lane == 0) red[w] = m;
    __syncthreads();
    m = fmaxf(fmaxf(red[0], red[1]), fmaxf(red[2], red[3]));
    __syncthreads();
    float sum = 0.f;
    for (int i = tid; i < NN; i += 256) sum += __expf(s[i] - m);
    #pragma unroll
    for (int off = 32; off; off >>= 1) sum += __shfl_xor(sum, off);
    if (lane == 0) red[w] = sum;
    __syncthreads();
    sum = red[0] + red[1] + red[2] + red[3];
    const float inv = 1.f / sum;
    for (int i = tid; i < NN; i += 256) p[b*NN + i] = __expf(s[i] - m) * inv;
}

// ---------------- K3: per-chunk partial weighted sum (xbar) and plain sum (gapx) over rows
__global__ __launch_bounds__(256) void k_wsum(const float* __restrict__ x,
        const float* __restrict__ p,
        float* __restrict__ part_xbar, float* __restrict__ part_gap)
{
    const int b  = blockIdx.x / CHUNKS;
    const int ch = blockIdx.x % CHUNKS;
    const int tid = threadIdx.x;                     // 256 threads, 2 channels each
    const long base = ((long)b * NN + (long)ch * RPC) * CC;
    const float* pb = p + b*NN + ch*RPC;
    float2 aw = {0.f, 0.f}, ag = {0.f, 0.f};
    for (int r = 0; r < RPC; ++r) {
        float2 v = *(const float2*)(x + base + (long)r*CC + 2*tid);
        float pr = pb[r];
        ag.x += v.x;             ag.y += v.y;
        aw.x = fmaf(pr, v.x, aw.x); aw.y = fmaf(pr, v.y, aw.y);
    }
    const int o = (b*CHUNKS + ch)*CC + 2*tid;
    *(float2*)(part_xbar + o) = aw;
    *(float2*)(part_gap  + o) = ag;
}

// ---------------- K3b: reduce chunk partials -> xbar (B,C), gapx (B,C)   (deterministic)
__global__ __launch_bounds__(256) void k_reduce(const float* __restrict__ part_xbar,
        const float* __restrict__ part_gap,
        float* __restrict__ xbar, float* __restrict__ gapx)
{
    const int g = blockIdx.x * 256 + threadIdx.x;    // 0..B*C-1
    const int b = g / CC, c = g % CC;
    float sx = 0.f, sg = 0.f;
    for (int k = 0; k < CHUNKS; ++k) {
        sx += part_xbar[(b*CHUNKS + k)*CC + c];
        sg += part_gap [(b*CHUNKS + k)*CC + c];
    }
    xbar[g] = sx; gapx[g] = sg;
}

// ---------------- K4: all per-batch small math -> cw (B,C), veff (B,C), constb (B)
__global__ __launch_bounds__(256) void k_small(
    const float* __restrict__ xbar, const float* __restrict__ gapx,
    const float* __restrict__ ch_wv_w, const float* __restrict__ ch_wv_b,
    const float* __restrict__ ch_wz_w, const float* __restrict__ ch_wz_b,
    const float* __restrict__ ln_g,    const float* __restrict__ ln_b,
    const float* __restrict__ sp_wv_w, const float* __restrict__ sp_wv_b,
    const float* __restrict__ sp_wq_w, const float* __restrict__ sp_wq_b,
    float* __restrict__ cw, float* __restrict__ veff, float* __restrict__ constb)
{
    const int b = blockIdx.x, tid = threadIdx.x, lane = tid & 63, w = tid >> 6;
    __shared__ float s_vec[CC];
    __shared__ float s_mid[C2];
    __shared__ float s_cw[CC];
    __shared__ float s_red[8];

    s_vec[tid]       = xbar[b*CC + tid];
    s_vec[tid + 256] = xbar[b*CC + tid + 256];
    __syncthreads();

    // ch_wz1[d] = xbar·ch_wv_w[:,d] + b   (sum over n of p gives exactly +bias)
    float acc = ch_wv_b[tid];
    for (int c = 0; c < CC; ++c) acc = fmaf(s_vec[c], ch_wv_w[c*C2 + tid], acc);
    __syncthreads();
    s_mid[tid] = acc;
    __syncthreads();

    // ch_wz2[c] = wz1·ch_wz_w[:,c] + b,  two c per thread
    float z0 = ch_wz_b[tid], z1 = ch_wz_b[tid + 256];
    for (int d = 0; d < C2; ++d) {
        float m = s_mid[d];
        z0 = fmaf(m, ch_wz_w[d*CC + tid],       z0);
        z1 = fmaf(m, ch_wz_w[d*CC + tid + 256], z1);
    }

    // LayerNorm over C (biased var, eps inside rsqrt) + sigmoid
    float sum = z0 + z1, sq = z0*z0 + z1*z1;
    #pragma unroll
    for (int off = 32; off; off >>= 1) { sum += __shfl_xor(sum, off); sq += __shfl_xor(sq, off); }
    if (lane == 0) { s_red[w] = sum; s_red[4 + w] = sq; }
    __syncthreads();
    sum = s_red[0] + s_red[1] + s_red[2] + s_red[3];
    sq  = s_red[4] + s_red[5] + s_red[6] + s_red[7];
    const float mean = sum * (1.f/CC);
    const float var  = sq  * (1.f/CC) - mean*mean;
    const float rstd = rsqrtf(var + 1e-3f);
    float cw0 = sigmoidf_((z0 - mean)*rstd*ln_g[tid]       + ln_b[tid]);
    float cw1 = sigmoidf_((z1 - mean)*rstd*ln_g[tid + 256] + ln_b[tid + 256]);
    s_cw[tid] = cw0; s_cw[tid + 256] = cw1;
    cw[b*CC + tid] = cw0; cw[b*CC + tid + 256] = cw1;
    __syncthreads();

    // gap of channel_out = cw * gapx / N
    s_vec[tid]       = cw0 * gapx[b*CC + tid]       * (1.f/NN);
    s_vec[tid + 256] = cw1 * gapx[b*CC + tid + 256] * (1.f/NN);
    __syncthreads();

    // sp_wq[d] = gap_co·sp_wq_w[:,d] + b ; softmax over C2
    float q = sp_wq_b[tid];
    for (int c = 0; c < CC; ++c) q = fmaf(s_vec[c], sp_wq_w[c*C2 + tid], q);
    float mx = q;
    #pragma unroll
    for (int off = 32; off; off >>= 1) mx = fmaxf(mx, __shfl_xor(mx, off));
    if (lane == 0) s_red[w] = mx;
    __syncthreads();
    mx = fmaxf(fmaxf(s_red[0], s_red[1]), fmaxf(s_red[2], s_red[3]));
    __syncthreads();
    float e = __expf(q - mx);
    float se = e;
    #pragma unroll
    for (int off = 32; off; off >>= 1) se += __shfl_xor(se, off);
    if (lane == 0) s_red[w] = se;
    __syncthreads();
    se = s_red[0] + s_red[1] + s_red[2] + s_red[3];
    const float qn = e / se;
    s_mid[tid] = qn;

    // constb = q·sp_wv_b
    float cb = sp_wv_b[tid] * qn;
    #pragma unroll
    for (int off = 32; off; off >>= 1) cb += __shfl_xor(cb, off);
    __syncthreads();                      // also publishes s_mid
    if (lane == 0) s_red[w] = cb;
    __syncthreads();
    cb = s_red[0] + s_red[1] + s_red[2] + s_red[3];
    if (tid == 0) constb[b] = cb;

    // v_eff[c] = cw[c] * (sp_wv_w[c,:]·q),  two c per thread
    float w0 = 0.f, w1 = 0.f;
    for (int d = 0; d < C2; ++d) {
        float qq = s_mid[d];
        w0 = fmaf(sp_wv_w[tid*C2 + d],         qq, w0);
        w1 = fmaf(sp_wv_w[(tid + 256)*C2 + d], qq, w1);
    }
    veff[b*CC + tid]       = s_cw[tid]       * w0;
    veff[b*CC + tid + 256] = s_cw[tid + 256] * w1;
}

// ---------------- K5: out[b,n,c] = sigmoid(x[b,n,:]·veff[b] + constb[b]) * cw[b,c] * x[b,n,c]
__global__ __launch_bounds__(256) void k_final(const float* __restrict__ x,
        const float* __restrict__ cw, const float* __restrict__ veff,
        const float* __restrict__ constb, float* __restrict__ out)
{
    const int lane = threadIdx.x & 63;
    const int wv   = threadIdx.x >> 6;
    const long row = (long)blockIdx.x * 4 + wv;
    const int b = (int)(row >> 12);                  // N = 4096
    const float* xr = x + row * CC;
    float4 a0 = *(const float4*)(xr + lane*4);
    float4 a1 = *(const float4*)(xr + 256 + lane*4);
    const float* vb = veff + b*CC;
    float4 v0 = *(const float4*)(vb + lane*4);
    float4 v1 = *(const float4*)(vb + 256 + lane*4);
    float d = a0.x*v0.x + a0.y*v0.y + a0.z*v0.z + a0.w*v0.w
            + a1.x*v1.x + a1.y*v1.y + a1.z*v1.z + a1.w*v1.w;
    #pragma unroll
    for (int off = 32; off; off >>= 1) d += __shfl_xor(d, off);   // butterfly: all lanes get it
    const float sw = sigmoidf_(d + constb[b]);
    const float* cb = cw + b*CC;
    float4 c0 = *(const float4*)(cb + lane*4);
    float4 c1 = *(const float4*)(cb + 256 + lane*4);
    float4 o0, o1;
    o0.x = sw*c0.x*a0.x; o0.y = sw*c0.y*a0.y; o0.z = sw*c0.z*a0.z; o0.w = sw*c0.w*a0.w;
    o1.x = sw*c1.x*a1.x; o1.y = sw*c1.y*a1.y; o1.z = sw*c1.z*a1.z; o1.w = sw*c1.w*a1.w;
    *(float4*)(out + row*CC + lane*4)       = o0;
    *(float4*)(out + row*CC + 256 + lane*4) = o1;
}

extern "C" void kernel_launch(void* const* d_in, const int* in_sizes, int n_in,
                              void* d_out, int out_size, void* d_ws, size_t ws_size,
                              hipStream_t stream)
{
    const float* x       = (const float*)d_in[0];
    const float* ch_wv_w = (const float*)d_in[1];
    const float* ch_wv_b = (const float*)d_in[2];
    const float* ch_wq_w = (const float*)d_in[3];
    const float* ch_wq_b = (const float*)d_in[4];
    const float* ch_wz_w = (const float*)d_in[5];
    const float* ch_wz_b = (const float*)d_in[6];
    const float* ln_g    = (const float*)d_in[7];
    const float* ln_b    = (const float*)d_in[8];
    const float* sp_wv_w = (const float*)d_in[9];
    const float* sp_wv_b = (const float*)d_in[10];
    const float* sp_wq_w = (const float*)d_in[11];
    const float* sp_wq_b = (const float*)d_in[12];
    float* out = (float*)d_out;

    float* ws = (float*)d_ws;
    float* s1        = ws;                            // B*N
    float* p         = s1 + BB*NN;                    // B*N
    float* part_xbar = p + BB*NN;                     // B*CHUNKS*C
    float* part_gap  = part_xbar + BB*CHUNKS*CC;      // B*CHUNKS*C
    float* xbar      = part_gap + BB*CHUNKS*CC;       // B*C
    float* gapx      = xbar + BB*CC;                  // B*C
    float* cw        = gapx + BB*CC;                  // B*C
    float* veff      = cw + BB*CC;                    // B*C
    float* constb    = veff + BB*CC;                  // B

    k_logits   <<<BB*NN/4, 256, 0, stream>>>(x, ch_wq_w, ch_wq_b, s1);
    k_softmax_n<<<BB,      256, 0, stream>>>(s1, p);
    k_wsum     <<<BB*CHUNKS, 256, 0, stream>>>(x, p, part_xbar, part_gap);
    k_reduce   <<<BB*CC/256, 256, 0, stream>>>(part_xbar, part_gap, xbar, gapx);
    k_small    <<<BB,      256, 0, stream>>>(xbar, gapx, ch_wv_w, ch_wv_b, ch_wz_w, ch_wz_b,
                                             ln_g, ln_b, sp_wv_w, sp_wv_b, sp_wq_w, sp_wq_b,
                                             cw, veff, constb);
    k_final    <<<BB*NN/4, 256, 0, stream>>>(x, cw, veff, constb, out);
}

// Round 3
// 107.043 us; speedup vs baseline: 1.4174x; 1.4174x over previous
//
#include <hip/hip_runtime.h>
#include <math.h>

#define BB 16
#define NN 4096
#define CC 512
#define C2 256
#define CHUNKS 32
#define RPC (NN/CHUNKS)   // 128 rows per chunk

__device__ __forceinline__ float sigmoidf_(float z){ return 1.0f/(1.0f + __expf(-z)); }
__device__ __forceinline__ float dot8_(float4 a0, float4 a1, float4 b0, float4 b1){
    return a0.x*b0.x + a0.y*b0.y + a0.z*b0.z + a0.w*b0.w
         + a1.x*b1.x + a1.y*b1.y + a1.z*b1.z + a1.w*b1.w;
}

// ---------- K1: one pass over x: per-chunk logits, online-softmax stats, weighted sum, plain sum
__global__ __launch_bounds__(256) void k_stats(const float* __restrict__ x,
        const float* __restrict__ wq,
        float* __restrict__ part_w, float* __restrict__ part_g,
        float* __restrict__ chunk_m, float* __restrict__ chunk_d)
{
    const int b = blockIdx.x / CHUNKS;
    const int k = blockIdx.x % CHUNKS;
    const int tid = threadIdx.x, lane = tid & 63, wv = tid >> 6;
    __shared__ float s_log[RPC];
    __shared__ float s_e[RPC];
    __shared__ float g_part[4][CC];          // 8 KB
    const long base = ((long)b*NN + (long)k*RPC) * CC;

    float4 w0 = *(const float4*)(wq + lane*4);
    float4 w1 = *(const float4*)(wq + 256 + lane*4);
    float g0x=0,g0y=0,g0z=0,g0w=0, g1x=0,g1y=0,g1z=0,g1w=0;

    // phase A: row-parallel logits (softmax is shift-invariant -> skip bias) + gap partials
    for (int i = 0; i < RPC/4; ++i) {
        const int r = wv*(RPC/4) + i;
        const float* xr = x + base + (long)r*CC;
        float4 a0 = *(const float4*)(xr + lane*4);
        float4 a1 = *(const float4*)(xr + 256 + lane*4);
        float d = dot8_(a0, a1, w0, w1);
        #pragma unroll
        for (int off = 32; off; off >>= 1) d += __shfl_xor(d, off);
        if (lane == 0) s_log[r] = d;
        g0x+=a0.x; g0y+=a0.y; g0z+=a0.z; g0w+=a0.w;
        g1x+=a1.x; g1y+=a1.y; g1z+=a1.z; g1w+=a1.w;
    }
    g_part[wv][lane*4+0]=g0x; g_part[wv][lane*4+1]=g0y;
    g_part[wv][lane*4+2]=g0z; g_part[wv][lane*4+3]=g0w;
    g_part[wv][256+lane*4+0]=g1x; g_part[wv][256+lane*4+1]=g1y;
    g_part[wv][256+lane*4+2]=g1z; g_part[wv][256+lane*4+3]=g1w;
    __syncthreads();

    // phase B: chunk max + exp
    float m = -3.4e38f;
    #pragma unroll
    for (int r = 0; r < RPC; ++r) m = fmaxf(m, s_log[r]);
    if (tid < RPC) s_e[tid] = __expf(s_log[tid] - m);
    __syncthreads();
    if (tid == 0) {
        float dsum = 0.f;
        for (int r = 0; r < RPC; ++r) dsum += s_e[r];
        chunk_d[b*CHUNKS + k] = dsum;
        chunk_m[b*CHUNKS + k] = m;
    }

    // phase C: channel-parallel weighted sum (x re-read is L2/L3-hot)
    const int c = 2*tid;
    float2 acc = {0.f, 0.f};
    for (int r = 0; r < RPC; ++r) {
        float2 v = *(const float2*)(x + base + (long)r*CC + c);
        float e = s_e[r];
        acc.x = fmaf(e, v.x, acc.x);
        acc.y = fmaf(e, v.y, acc.y);
    }
    *(float2*)(part_w + (long)(b*CHUNKS + k)*CC + c) = acc;
    float2 g;
    g.x = g_part[0][c]   + g_part[1][c]   + g_part[2][c]   + g_part[3][c];
    g.y = g_part[0][c+1] + g_part[1][c+1] + g_part[2][c+1] + g_part[3][c+1];
    *(float2*)(part_g + (long)(b*CHUNKS + k)*CC + c) = g;
}

// ---------- K2: combine chunk stats -> xbar (softmax-weighted mean), gapx (plain sum)
__global__ __launch_bounds__(256) void k_combine(const float* __restrict__ part_w,
        const float* __restrict__ part_g,
        const float* __restrict__ chunk_m, const float* __restrict__ chunk_d,
        float* __restrict__ xbar, float* __restrict__ gapx)
{
    const int b  = blockIdx.x >> 3;
    const int cs = blockIdx.x & 7;
    const int tid = threadIdx.x, cl = tid & 63, q = tid >> 6;
    const int c = cs*64 + cl;
    __shared__ float s_scale[CHUNKS];
    __shared__ float s_w[4][64];
    __shared__ float s_g[4][64];
    const float* cm = chunk_m + b*CHUNKS;
    const float* cd = chunk_d + b*CHUNKS;
    float m = -3.4e38f;
    #pragma unroll
    for (int k = 0; k < CHUNKS; ++k) m = fmaxf(m, cm[k]);
    if (tid < CHUNKS) s_scale[tid] = __expf(cm[tid] - m);
    __syncthreads();
    float denom = 0.f;
    #pragma unroll
    for (int k = 0; k < CHUNKS; ++k) denom = fmaf(s_scale[k], cd[k], denom);
    float pw = 0.f, pg = 0.f;
    for (int k = q*8; k < q*8+8; ++k) {
        pw = fmaf(s_scale[k], part_w[(long)(b*CHUNKS + k)*CC + c], pw);
        pg += part_g[(long)(b*CHUNKS + k)*CC + c];
    }
    s_w[q][cl] = pw; s_g[q][cl] = pg;
    __syncthreads();
    if (q == 0) {
        float sw_ = s_w[0][cl]+s_w[1][cl]+s_w[2][cl]+s_w[3][cl];
        float sg_ = s_g[0][cl]+s_g[1][cl]+s_g[2][cl]+s_g[3][cl];
        xbar[b*CC + c] = sw_ / denom;
        gapx[b*CC + c] = sg_;
    }
}

// ---------- G1/G3: out[b,d] = vec[b,:]·W[:,d] + bias[d]   (W row-major (512,256))
__global__ __launch_bounds__(256) void k_gemv_cd(const float* __restrict__ vec,
        const float* __restrict__ W, const float* __restrict__ bias,
        float* __restrict__ out)
{
    const int bx = blockIdx.x;          // d-tile (0..3)
    const int b  = blockIdx.y;
    const int tid = threadIdx.x, dl = tid & 63, q = tid >> 6;
    const int d = bx*64 + dl;
    __shared__ float s_x[CC];
    __shared__ float s_p[4][64];
    s_x[tid]       = vec[b*CC + tid];
    s_x[tid + 256] = vec[b*CC + tid + 256];
    __syncthreads();
    float a0=0,a1=0,a2=0,a3=0;
    #pragma unroll 8
    for (int c = q*128; c < q*128 + 128; c += 4) {
        a0 = fmaf(s_x[c+0], W[(c+0)*C2 + d], a0);
        a1 = fmaf(s_x[c+1], W[(c+1)*C2 + d], a1);
        a2 = fmaf(s_x[c+2], W[(c+2)*C2 + d], a2);
        a3 = fmaf(s_x[c+3], W[(c+3)*C2 + d], a3);
    }
    s_p[q][dl] = (a0+a1)+(a2+a3);
    __syncthreads();
    if (q == 0)
        out[b*C2 + d] = s_p[0][dl]+s_p[1][dl]+s_p[2][dl]+s_p[3][dl] + bias[d];
}

// ---------- G2 partial: part2[b,jd,c] = sum_{d in chunk jd} mid[b,d]*Wz[d,c]
__global__ __launch_bounds__(256) void k_g2p(const float* __restrict__ mid,
        const float* __restrict__ Wz, float* __restrict__ part2)
{
    const int jd = blockIdx.x;          // 0..7, 32 d's each
    const int b  = blockIdx.y;
    const int tid = threadIdx.x;
    __shared__ float s_m[32];
    if (tid < 32) s_m[tid] = mid[b*C2 + jd*32 + tid];
    __syncthreads();
    float a0 = 0.f, a1 = 0.f;
    #pragma unroll 8
    for (int dd = 0; dd < 32; ++dd) {
        const float mm = s_m[dd];
        const int d = jd*32 + dd;
        a0 = fmaf(mm, Wz[d*CC + tid],       a0);
        a1 = fmaf(mm, Wz[d*CC + tid + 256], a1);
    }
    part2[(long)(b*8 + jd)*CC + tid]       = a0;
    part2[(long)(b*8 + jd)*CC + tid + 256] = a1;
}

// ---------- G2 reduce + LayerNorm + sigmoid -> cw; gco = cw*gapx/N
__global__ __launch_bounds__(256) void k_g2ln(const float* __restrict__ part2,
        const float* __restrict__ bz, const float* __restrict__ ln_g,
        const float* __restrict__ ln_b, const float* __restrict__ gapx,
        float* __restrict__ cw, float* __restrict__ gco)
{
    const int b = blockIdx.x, tid = threadIdx.x, lane = tid & 63, w = tid >> 6;
    __shared__ float s_red[8];
    float z0 = bz[tid], z1 = bz[tid + 256];
    #pragma unroll
    for (int jd = 0; jd < 8; ++jd) {
        z0 += part2[(long)(b*8 + jd)*CC + tid];
        z1 += part2[(long)(b*8 + jd)*CC + tid + 256];
    }
    float sum = z0 + z1, sq = z0*z0 + z1*z1;
    #pragma unroll
    for (int off = 32; off; off >>= 1) { sum += __shfl_xor(sum, off); sq += __shfl_xor(sq, off); }
    if (lane == 0) { s_red[w] = sum; s_red[4 + w] = sq; }
    __syncthreads();
    sum = s_red[0] + s_red[1] + s_red[2] + s_red[3];
    sq  = s_red[4] + s_red[5] + s_red[6] + s_red[7];
    const float mean = sum * (1.f/CC);
    const float var  = sq  * (1.f/CC) - mean*mean;
    const float rstd = rsqrtf(var + 1e-3f);
    float cw0 = sigmoidf_((z0 - mean)*rstd*ln_g[tid]       + ln_b[tid]);
    float cw1 = sigmoidf_((z1 - mean)*rstd*ln_g[tid + 256] + ln_b[tid + 256]);
    cw[b*CC + tid]       = cw0;
    cw[b*CC + tid + 256] = cw1;
    gco[b*CC + tid]       = cw0 * gapx[b*CC + tid]       * (1.f/NN);
    gco[b*CC + tid + 256] = cw1 * gapx[b*CC + tid + 256] * (1.f/NN);
}

// ---------- G3 softmax over C2 + constb = qn·sp_wv_b
__global__ __launch_bounds__(256) void k_g3sm(const float* __restrict__ qraw,
        const float* __restrict__ svb, float* __restrict__ qn, float* __restrict__ constb)
{
    const int b = blockIdx.x, tid = threadIdx.x, lane = tid & 63, w = tid >> 6;
    __shared__ float s_red[4];
    float v = qraw[b*C2 + tid];
    float mx = v;
    #pragma unroll
    for (int off = 32; off; off >>= 1) mx = fmaxf(mx, __shfl_xor(mx, off));
    if (lane == 0) s_red[w] = mx;
    __syncthreads();
    mx = fmaxf(fmaxf(s_red[0], s_red[1]), fmaxf(s_red[2], s_red[3]));
    __syncthreads();
    float e = __expf(v - mx);
    float se = e;
    #pragma unroll
    for (int off = 32; off; off >>= 1) se += __shfl_xor(se, off);
    if (lane == 0) s_red[w] = se;
    __syncthreads();
    se = s_red[0] + s_red[1] + s_red[2] + s_red[3];
    const float q = e / se;
    qn[b*C2 + tid] = q;
    float cb = q * svb[tid];
    #pragma unroll
    for (int off = 32; off; off >>= 1) cb += __shfl_xor(cb, off);
    __syncthreads();
    if (lane == 0) s_red[w] = cb;
    __syncthreads();
    if (tid == 0) constb[b] = s_red[0] + s_red[1] + s_red[2] + s_red[3];
}

// ---------- G4: veff[b,c] = cw[b,c] * (sp_wv_w[c,:]·qn[b,:])   (row-contiguous dot)
__global__ __launch_bounds__(256) void k_veff(const float* __restrict__ Wv2,
        const float* __restrict__ qn, const float* __restrict__ cw,
        float* __restrict__ veff)
{
    const int lane = threadIdx.x & 63;
    const int wv   = threadIdx.x >> 6;
    const int gw = blockIdx.x*4 + wv;       // 0..8191  (grid = BB*CC/4 blocks)
    const int c = gw >> 4;                  // weight row reused across 16 b's
    const int b = gw & 15;
    float4 w4 = *(const float4*)(Wv2 + (long)c*C2 + lane*4);
    float4 q4 = *(const float4*)(qn + b*C2 + lane*4);
    float d = w4.x*q4.x + w4.y*q4.y + w4.z*q4.z + w4.w*q4.w;
    #pragma unroll
    for (int off = 32; off; off >>= 1) d += __shfl_xor(d, off);
    if (lane == 0) veff[b*CC + c] = cw[b*CC + c] * d;
}

// ---------- K5: out = sigmoid(x·veff + constb) * cw * x
__global__ __launch_bounds__(256) void k_final(const float* __restrict__ x,
        const float* __restrict__ cw, const float* __restrict__ veff,
        const float* __restrict__ constb, float* __restrict__ out)
{
    const int lane = threadIdx.x & 63;
    const int wv   = threadIdx.x >> 6;
    const long row = (long)blockIdx.x * 4 + wv;
    const int b = (int)(row >> 12);
    const float* xr = x + row * CC;
    float4 a0 = *(const float4*)(xr + lane*4);
    float4 a1 = *(const float4*)(xr + 256 + lane*4);
    const float* vb = veff + b*CC;
    float4 v0 = *(const float4*)(vb + lane*4);
    float4 v1 = *(const float4*)(vb + 256 + lane*4);
    float d = dot8_(a0, a1, v0, v1);
    #pragma unroll
    for (int off = 32; off; off >>= 1) d += __shfl_xor(d, off);
    const float sw = sigmoidf_(d + constb[b]);
    const float* cb = cw + b*CC;
    float4 c0 = *(const float4*)(cb + lane*4);
    float4 c1 = *(const float4*)(cb + 256 + lane*4);
    float4 o0, o1;
    o0.x = sw*c0.x*a0.x; o0.y = sw*c0.y*a0.y; o0.z = sw*c0.z*a0.z; o0.w = sw*c0.w*a0.w;
    o1.x = sw*c1.x*a1.x; o1.y = sw*c1.y*a1.y; o1.z = sw*c1.z*a1.z; o1.w = sw*c1.w*a1.w;
    *(float4*)(out + row*CC + lane*4)       = o0;
    *(float4*)(out + row*CC + 256 + lane*4) = o1;
}

extern "C" void kernel_launch(void* const* d_in, const int* in_sizes, int n_in,
                              void* d_out, int out_size, void* d_ws, size_t ws_size,
                              hipStream_t stream)
{
    const float* x       = (const float*)d_in[0];
    const float* ch_wv_w = (const float*)d_in[1];
    const float* ch_wv_b = (const float*)d_in[2];
    const float* ch_wq_w = (const float*)d_in[3];
    // d_in[4] = ch_wq_b: softmax shift-invariant, unused
    const float* ch_wz_w = (const float*)d_in[5];
    const float* ch_wz_b = (const float*)d_in[6];
    const float* ln_g    = (const float*)d_in[7];
    const float* ln_b    = (const float*)d_in[8];
    const float* sp_wv_w = (const float*)d_in[9];
    const float* sp_wv_b = (const float*)d_in[10];
    const float* sp_wq_w = (const float*)d_in[11];
    const float* sp_wq_b = (const float*)d_in[12];
    float* out = (float*)d_out;

    float* ws = (float*)d_ws;
    float* part_w  = ws;                           // B*CHUNKS*C
    float* part_g  = part_w + BB*CHUNKS*CC;
    float* chunk_m = part_g + BB*CHUNKS*CC;
    float* chunk_d = chunk_m + BB*CHUNKS;
    float* xbar    = chunk_d + BB*CHUNKS;
    float* gapx    = xbar + BB*CC;
    float* mid     = gapx + BB*CC;
    float* part2   = mid + BB*C2;
    float* cw      = part2 + BB*8*CC;
    float* gco     = cw + BB*CC;
    float* qraw    = gco + BB*CC;
    float* qn      = qraw + BB*C2;
    float* constb  = qn + BB*C2;
    float* veff    = constb + BB;

    k_stats  <<<BB*CHUNKS, 256, 0, stream>>>(x, ch_wq_w, part_w, part_g, chunk_m, chunk_d);
    k_combine<<<BB*8,      256, 0, stream>>>(part_w, part_g, chunk_m, chunk_d, xbar, gapx);
    k_gemv_cd<<<dim3(4,BB),256, 0, stream>>>(xbar, ch_wv_w, ch_wv_b, mid);
    k_g2p    <<<dim3(8,BB),256, 0, stream>>>(mid, ch_wz_w, part2);
    k_g2ln   <<<BB,        256, 0, stream>>>(part2, ch_wz_b, ln_g, ln_b, gapx, cw, gco);
    k_gemv_cd<<<dim3(4,BB),256, 0, stream>>>(gco, sp_wq_w, sp_wq_b, qraw);
    k_g3sm   <<<BB,        256, 0, stream>>>(qraw, sp_wv_b, qn, constb);
    k_veff   <<<BB*CC/4,   256, 0, stream>>>(sp_wv_w, qn, cw, veff);   // FIX: was BB*CC/16
    k_final  <<<BB*NN/4,   256, 0, stream>>>(x, cw, veff, constb, out);
}